// Round 6
// baseline (133.103 us; speedup 1.0000x reference)
//
#include <hip/hip_runtime.h>
#include <hip/hip_bf16.h>

// DiffAlphaSplitModel: VOCAB=64, H=64, HALF=32, B=256, L=2048.
//  1) 64 distinct tokens -> per-vocab tables: k (normalized), h (raw),
//     Gram G[v][w] = k_v . k_w per chain.
//  2) r = M_L q via backward recurrence, CHUNKED (T=32):
//       d_q = g_q - sum_{ps>q} c_ps G[t_q][t_ps] d_ps   (triangular solve)
//  3) DUAL-SPACE state: gf_v = k_v . u for all 64 vocab (lane = v).
//  4) THIS ROUND:
//     a) 2-deep software pipeline: chunk ci+1's token-only gathers (ta, tq,
//        aW, Gc) are issued during chunk ci's solve (double-banked, static
//        indexing). bpermute issued FIRST each iteration; in-order DS
//        completion means waiting for it does not drain the prefetches.
//     b) r accumulated in VOCAB space: w_v += sum_q e_q [ta_q == v]
//        (compare/select, no LDS) ; r = sum_v w_v h[v] once at the end.
//        Removes the 32 Hc reads per chunk (105 -> 73 DS/chunk).
//  s-chain and e-chain in separate waves (block=128). No barriers/LDS writes
//  in the main loop.
//
// ws layout (floats):
//   [0     ..  4095] compact k [2][64][32]
//   [4096  ..  8191] compact h [2][64][32]
//   [16384 .. 24575] Gram [2][64][64]
//   [24576 .. 40959] rbuf [256][64]

#define L_SEQ 2048
#define NPOS  2047
#define TCH   32
#define NCH   64

__device__ __forceinline__ float rdlane(float v, int l) {
    return __int_as_float(__builtin_amdgcn_readlane(__float_as_int(v), l));
}

// ---------------- Kernel A: per-vocab tables -------------------------------
__global__ void build_tables(const float* __restrict__ embed,
                             const float* __restrict__ w1, const float* __restrict__ b1,
                             const float* __restrict__ w2, const float* __restrict__ b2,
                             const float* __restrict__ ln_g, const float* __restrict__ ln_b,
                             const float* __restrict__ ws, const float* __restrict__ bs,
                             const float* __restrict__ we, const float* __restrict__ be,
                             float* __restrict__ tabs) {
    const int v = blockIdx.x;
    const int t = threadIdx.x;        // 0..63
    __shared__ float sh_h[64];
    __shared__ float sh_a[128];
    __shared__ float sh_x[64];

    sh_h[t] = embed[v * 64 + t];
    __syncthreads();

    float acc0 = b1[t], acc1 = b1[t + 64];
    #pragma unroll 8
    for (int k = 0; k < 64; ++k) {
        const float hv = sh_h[k];
        acc0 += hv * w1[k * 128 + t];
        acc1 += hv * w1[k * 128 + t + 64];
    }
    sh_a[t]      = fmaxf(acc0, 0.f);
    sh_a[t + 64] = fmaxf(acc1, 0.f);
    __syncthreads();

    float x = sh_h[t] + b2[t];
    #pragma unroll 8
    for (int k = 0; k < 128; ++k) x += sh_a[k] * w2[k * 64 + t];

    float mu = x;
    for (int m = 1; m <= 32; m <<= 1) mu += __shfl_xor(mu, m);
    mu *= (1.f / 64.f);
    const float dx = x - mu;
    float var = dx * dx;
    for (int m = 1; m <= 32; m <<= 1) var += __shfl_xor(var, m);
    var *= (1.f / 64.f);
    const float hln = dx * rsqrtf(var + 1e-5f) * ln_g[t] + ln_b[t];
    sh_x[t] = hln;
    __syncthreads();

    const int j   = t & 31;
    const int mem = t >> 5;
    const float* W  = mem ? we : ws;
    const float* Bv = mem ? be : bs;
    float p = Bv[j];
    #pragma unroll 8
    for (int k = 0; k < 64; ++k) p += sh_x[k] * W[k * 32 + j];

    float nn = p * p;
    for (int m = 1; m <= 16; m <<= 1) nn += __shfl_xor(nn, m);
    const float kn = p / fmaxf(sqrtf(nn), 1e-12f);

    tabs[(mem * 64 + v) * 32 + j]        = kn;   // normalized key
    tabs[4096 + (mem * 64 + v) * 32 + j] = p;    // raw projection
}

// ---------------- Kernel A2: Gram tables -----------------------------------
__global__ void gram_kernel(const float* __restrict__ tabs, float* __restrict__ gout) {
    const int v  = blockIdx.x;
    const int tt = threadIdx.x;          // 0..127
    const int m  = tt >> 6, w = tt & 63;
    __shared__ float kv[64];
    if (tt < 64) kv[tt] = tabs[((tt >> 5) * 64 + v) * 32 + (tt & 31)];
    __syncthreads();
    const float* kw  = &tabs[(m * 64 + w) * 32];
    const float* kvm = &kv[m * 32];
    float acc = 0.f;
    #pragma unroll 8
    for (int j = 0; j < 32; ++j) acc += kvm[j] * kw[j];
    gout[m * 4096 + v * 64 + w] = acc;
}

// ======== per-chunk macros (static indexing; banks are named arrays) ========
// PREP: token-only gathers for chunk CI -> {TA_P (8 packed ints), AW, GC, TQ}
#define PREP(CI, TA_P, AW, GC, TQ)                                            \
  do {                                                                        \
    const int t_ = NPOS - TCH * ((CI) + 1);                                   \
    const int4* tp4_ = (const int4*)&seq_sh[t_];                              \
    int tta_[TCH];                                                            \
    _Pragma("unroll")                                                         \
    for (int k2 = 0; k2 < 8; ++k2) {                                          \
      int4 vv_ = tp4_[k2];                                                    \
      tta_[4*k2+0]=vv_.x; tta_[4*k2+1]=vv_.y;                                 \
      tta_[4*k2+2]=vv_.z; tta_[4*k2+3]=vv_.w;                                 \
    }                                                                         \
    TQ = seq_sh[t_ + q];                                                      \
    const float* growq_ = &gt[m * 4160 + (TQ) * 65];                          \
    const float cf0_ = m ? (float)(t_ + 1) * invL : 1.0f;                     \
    const float cfs_ = m ? invL : 0.0f;                                       \
    float cf_ = cf0_;                                                         \
    _Pragma("unroll")                                                         \
    for (int ps = 1; ps < TCH; ++ps) {                                        \
      cf_ += cfs_;                                                            \
      const float gv_ = growq_[tta_[ps]];                                     \
      AW[ps] = (q < ps) ? cf_ * gv_ : 0.f;                                    \
    }                                                                         \
    const float* growv_ = &gt[m * 4160 + lane * 65];                          \
    _Pragma("unroll")                                                         \
    for (int qq = 0; qq < TCH; ++qq) GC[qq] = growv_[tta_[qq]];               \
    _Pragma("unroll")                                                         \
    for (int k2 = 0; k2 < 8; ++k2)                                            \
      TA_P[k2] = tta_[4*k2] | (tta_[4*k2+1] << 8) |                           \
                 (tta_[4*k2+2] << 16) | (tta_[4*k2+3] << 24);                 \
  } while (0)

// SOLVE_UPDATE: triangular solve + state update for chunk CI using a bank
#define SOLVE_UPDATE(CI, TA_P, AW, GC, GQ)                                    \
  do {                                                                        \
    const int t_ = NPOS - TCH * ((CI) + 1);                                   \
    float dv_ = (GQ);                                                         \
    _Pragma("unroll")                                                         \
    for (int ps = TCH - 1; ps >= 1; --ps)                                     \
      dv_ = fmaf(-AW[ps], rdlane(dv_, ps), dv_);                              \
    const int   pq_ = t_ + q;                                                 \
    const float cq_ = m ? (float)(pq_ + 1) * invL : 1.0f;                     \
    const float ev_ = (pq_ >= 0) ? cq_ * dv_ : 0.f;                           \
    float gA_=0.f, gB_=0.f, wA_=0.f, wB_=0.f;                                 \
    _Pragma("unroll")                                                         \
    for (int qq = 0; qq < TCH; qq += 2) {                                     \
      const float e0_ = rdlane(ev_, qq);                                      \
      const float e1_ = rdlane(ev_, qq + 1);                                  \
      const int   p_  = TA_P[qq >> 2];                                        \
      const int   t0_ = (p_ >> ((qq & 3) * 8)) & 63;                          \
      const int   t1_ = (p_ >> (((qq + 1) & 3) * 8)) & 63;                    \
      gA_ = fmaf(e0_, GC[qq],     gA_);                                       \
      gB_ = fmaf(e1_, GC[qq + 1], gB_);                                       \
      wA_ += (lane == t0_) ? e0_ : 0.f;                                       \
      wB_ += (lane == t1_) ? e1_ : 0.f;                                       \
    }                                                                         \
    gf -= gA_ + gB_;                                                          \
    w  += wA_ + wB_;                                                          \
  } while (0)

// ---------------- Kernel B: chunked backward scan (dual-space, pipelined) --
// grid 256 (batch), block 128 = 2 waves. wave 0: s-chain (c=1), wave 1: e-chain.
// lane (0..63) = vocab id v for gf/w;  q = lane&31 = chunk position for solve.
__global__ void __launch_bounds__(128, 1) scan_kernel(const int* __restrict__ seq,
                                                      const float* __restrict__ tabs,
                                                      float* __restrict__ rbuf) {
    const int b    = blockIdx.x;
    const int tid  = threadIdx.x;        // 0..127
    const int m    = tid >> 6;           // wave id == chain id
    const int lane = tid & 63;           // vocab id v
    const int q    = lane & 31;          // chunk position

    __shared__ float gt [2 * 64 * 65];   // Gram rows padded to 65
    __shared__ float hsh[2 * 64 * 32];   // h tables [m][v][j]
    __shared__ int   seq_raw[2052];      // [0] = dummy token for p = -1
    int* seq_sh = seq_raw + 1;

    // ---- stage (one-time) ----
    for (int i = tid; i < 8192; i += 128) {
        const int mm = i >> 12, v = (i >> 6) & 63, ww = i & 63;
        gt[mm * 4160 + v * 65 + ww] = tabs[16384 + i];
    }
    for (int i = tid; i < 1024; i += 128)
        ((float4*)hsh)[i] = ((const float4*)(tabs + 4096))[i];
    if (tid == 0) seq_raw[0] = 0;
    {
        const int4* s4 = (const int4*)(seq + b * L_SEQ);
        for (int i = tid; i < 512; i += 128) {
            int4 vv = s4[i];
            seq_sh[i * 4 + 0] = vv.x; seq_sh[i * 4 + 1] = vv.y;
            seq_sh[i * 4 + 2] = vv.z; seq_sh[i * 4 + 3] = vv.w;
        }
    }
    __syncthreads();

    // ---- init: u = k_tokL  =>  gf_v = G[v][tokL];  w = vocab-space r ----
    const int tokL = seq_sh[NPOS];
    float gf = gt[m * 4160 + lane * 65 + tokL];
    float w  = 0.f;
    const float invL = 1.0f / (float)L_SEQ;

    int   taA[8], taB[8];
    float aWA[TCH], GcA[TCH], aWB[TCH], GcB[TCH];
    int   tqA, tqB;

    PREP(0, taA, aWA, GcA, tqA);

    for (int ci = 0; ci < NCH; ci += 2) {
        if (__all(fabsf(gf) < 1e-6f)) break;    // residual-based exit (per wave)

        // ---- chunk ci: bank A; prefetch ci+1 -> bank B ----
        {
            const float gq = __int_as_float(
                __builtin_amdgcn_ds_bpermute(tqA << 2, __float_as_int(gf)));
            PREP(ci + 1, taB, aWB, GcB, tqB);   // ci+1 <= 63 always
            SOLVE_UPDATE(ci, taA, aWA, GcA, gq);
        }

        // ---- chunk ci+1: bank B; prefetch ci+2 -> bank A ----
        {
            const float gq = __int_as_float(
                __builtin_amdgcn_ds_bpermute(tqB << 2, __float_as_int(gf)));
            const int cn = (ci + 2 < NCH) ? (ci + 2) : (NCH - 1);
            PREP(cn, taA, aWA, GcA, tqA);
            SOLVE_UPDATE(ci + 1, taB, aWB, GcB, gq);
        }
    }

    // ---- final: r_q = sum_v w_v * h[v][q] ----
    float r = 0.f;
    #pragma unroll 8
    for (int v = 0; v < 64; ++v) {
        const float wv = rdlane(w, v);
        r = fmaf(wv, hsh[(m * 64 + v) * 32 + q], r);
    }

    if (lane < 32)
        rbuf[b * 64 + m * 32 + q] = r;   // [rs | re] = concat order
}

// ---------------- Kernel C: output projection ------------------------------
__global__ void out_kernel(const float* __restrict__ rbuf,
                           const float* __restrict__ wrp, const float* __restrict__ brp,
                           const float* __restrict__ wout, const float* __restrict__ bout,
                           float* __restrict__ out) {
    const int b = blockIdx.x;
    const int t = threadIdx.x;
    __shared__ float rsh[64];
    __shared__ float ysh[64];

    rsh[t] = rbuf[b * 64 + t];
    __syncthreads();

    float y = brp[t];
    #pragma unroll 8
    for (int k = 0; k < 64; ++k) y += rsh[k] * wrp[k * 64 + t];
    ysh[t] = y;
    __syncthreads();

    float o = bout[t];
    #pragma unroll 8
    for (int k = 0; k < 64; ++k) o += ysh[k] * wout[k * 64 + t];
    out[b * 64 + t] = o;
}

// ---------------- launch ----------------------------------------------------
extern "C" void kernel_launch(void* const* d_in, const int* in_sizes, int n_in,
                              void* d_out, int out_size, void* d_ws, size_t ws_size,
                              hipStream_t stream) {
    const int*   seq   = (const int*)  d_in[0];
    const float* embed = (const float*)d_in[1];
    const float* w1    = (const float*)d_in[2];
    const float* b1    = (const float*)d_in[3];
    const float* w2    = (const float*)d_in[4];
    const float* b2    = (const float*)d_in[5];
    const float* ln_g  = (const float*)d_in[6];
    const float* ln_b  = (const float*)d_in[7];
    const float* ws    = (const float*)d_in[8];
    const float* bs    = (const float*)d_in[9];
    const float* we    = (const float*)d_in[10];
    const float* be    = (const float*)d_in[11];
    const float* wrp   = (const float*)d_in[12];
    const float* brp   = (const float*)d_in[13];
    const float* wout  = (const float*)d_in[14];
    const float* bout  = (const float*)d_in[15];

    float* tabs = (float*)d_ws;              // tables + gram
    float* gout = tabs + 16384;              // gram [2][64][64]
    float* rbuf = tabs + 24576;              // r vectors [256][64]

    build_tables<<<64, 64, 0, stream>>>(embed, w1, b1, w2, b2, ln_g, ln_b,
                                        ws, bs, we, be, tabs);
    gram_kernel<<<64, 128, 0, stream>>>(tabs, gout);
    scan_kernel<<<256, 128, 0, stream>>>(seq, tabs, rbuf);
    out_kernel<<<256, 64, 0, stream>>>(rbuf, wrp, brp, wout, bout, (float*)d_out);
}

// Round 7
// 98.008 us; speedup vs baseline: 1.3581x; 1.3581x over previous
//
#include <hip/hip_runtime.h>
#include <hip/hip_bf16.h>

// DiffAlphaSplitModel: VOCAB=64, H=64, HALF=32, B=256, L=2048.
//  1) 64 distinct tokens -> per-vocab tables: k (normalized), h (raw),
//     Gram G[v][w] = k_v . k_w per chain.
//  2) r = M_L q via backward recurrence, CHUNKED (T=32):
//       d_q = g_q - sum_{ps>q} c_ps G[t_q][t_ps] d_ps   (triangular solve)
//  3) DUAL-SPACE state: gf_v = k_v . u for all 64 vocab (lane = v).
//     r accumulated in VOCAB space (w_v), applied to h once at the end.
//  4) THIS ROUND: single-bank loop + sched_barrier(0) fence between the
//     gather batch {bpermute, aW, Gc} and the solve. Round 6's two-bank
//     pipeline regressed because the register allocator re-sank the gathers
//     into consumers (VGPR stayed 132); the fence FORCES one batched
//     lgkmcnt wall instead of ~31 serialized 120-cy gather latencies.
//  s-chain and e-chain in separate waves (block=128). No barriers/LDS writes
//  in the main loop.
//
// ws layout (floats):
//   [0     ..  4095] compact k [2][64][32]
//   [4096  ..  8191] compact h [2][64][32]
//   [16384 .. 24575] Gram [2][64][64]
//   [24576 .. 40959] rbuf [256][64]

#define L_SEQ 2048
#define NPOS  2047
#define TCH   32
#define NCH   64

__device__ __forceinline__ float rdlane(float v, int l) {
    return __int_as_float(__builtin_amdgcn_readlane(__float_as_int(v), l));
}

// ---------------- Kernel A: per-vocab tables -------------------------------
__global__ void build_tables(const float* __restrict__ embed,
                             const float* __restrict__ w1, const float* __restrict__ b1,
                             const float* __restrict__ w2, const float* __restrict__ b2,
                             const float* __restrict__ ln_g, const float* __restrict__ ln_b,
                             const float* __restrict__ ws, const float* __restrict__ bs,
                             const float* __restrict__ we, const float* __restrict__ be,
                             float* __restrict__ tabs) {
    const int v = blockIdx.x;
    const int t = threadIdx.x;        // 0..63
    __shared__ float sh_h[64];
    __shared__ float sh_a[128];
    __shared__ float sh_x[64];

    sh_h[t] = embed[v * 64 + t];
    __syncthreads();

    float acc0 = b1[t], acc1 = b1[t + 64];
    #pragma unroll 8
    for (int k = 0; k < 64; ++k) {
        const float hv = sh_h[k];
        acc0 += hv * w1[k * 128 + t];
        acc1 += hv * w1[k * 128 + t + 64];
    }
    sh_a[t]      = fmaxf(acc0, 0.f);
    sh_a[t + 64] = fmaxf(acc1, 0.f);
    __syncthreads();

    float x = sh_h[t] + b2[t];
    #pragma unroll 8
    for (int k = 0; k < 128; ++k) x += sh_a[k] * w2[k * 64 + t];

    float mu = x;
    for (int m = 1; m <= 32; m <<= 1) mu += __shfl_xor(mu, m);
    mu *= (1.f / 64.f);
    const float dx = x - mu;
    float var = dx * dx;
    for (int m = 1; m <= 32; m <<= 1) var += __shfl_xor(var, m);
    var *= (1.f / 64.f);
    const float hln = dx * rsqrtf(var + 1e-5f) * ln_g[t] + ln_b[t];
    sh_x[t] = hln;
    __syncthreads();

    const int j   = t & 31;
    const int mem = t >> 5;
    const float* W  = mem ? we : ws;
    const float* Bv = mem ? be : bs;
    float p = Bv[j];
    #pragma unroll 8
    for (int k = 0; k < 64; ++k) p += sh_x[k] * W[k * 32 + j];

    float nn = p * p;
    for (int m = 1; m <= 16; m <<= 1) nn += __shfl_xor(nn, m);
    const float kn = p / fmaxf(sqrtf(nn), 1e-12f);

    tabs[(mem * 64 + v) * 32 + j]        = kn;   // normalized key
    tabs[4096 + (mem * 64 + v) * 32 + j] = p;    // raw projection
}

// ---------------- Kernel A2: Gram tables -----------------------------------
__global__ void gram_kernel(const float* __restrict__ tabs, float* __restrict__ gout) {
    const int v  = blockIdx.x;
    const int tt = threadIdx.x;          // 0..127
    const int m  = tt >> 6, w = tt & 63;
    __shared__ float kv[64];
    if (tt < 64) kv[tt] = tabs[((tt >> 5) * 64 + v) * 32 + (tt & 31)];
    __syncthreads();
    const float* kw  = &tabs[(m * 64 + w) * 32];
    const float* kvm = &kv[m * 32];
    float acc = 0.f;
    #pragma unroll 8
    for (int j = 0; j < 32; ++j) acc += kvm[j] * kw[j];
    gout[m * 4096 + v * 64 + w] = acc;
}

// ---------------- Kernel B: chunked backward scan (dual-space) -------------
// grid 256 (batch), block 128 = 2 waves. wave 0: s-chain (c=1), wave 1: e-chain.
// lane (0..63) = vocab id v for gf/w;  q = lane&31 = chunk position for solve.
__global__ void __launch_bounds__(128, 1) scan_kernel(const int* __restrict__ seq,
                                                      const float* __restrict__ tabs,
                                                      float* __restrict__ rbuf) {
    const int b    = blockIdx.x;
    const int tid  = threadIdx.x;        // 0..127
    const int m    = tid >> 6;           // wave id == chain id
    const int lane = tid & 63;           // vocab id v
    const int q    = lane & 31;          // chunk position

    __shared__ float gt [2 * 64 * 65];   // Gram rows padded to 65
    __shared__ float hsh[2 * 64 * 32];   // h tables [m][v][j]
    __shared__ int   seq_raw[2052];      // [0] = dummy token for p = -1
    int* seq_sh = seq_raw + 1;

    // ---- stage (one-time) ----
    for (int i = tid; i < 8192; i += 128) {
        const int mm = i >> 12, v = (i >> 6) & 63, ww = i & 63;
        gt[mm * 4160 + v * 65 + ww] = tabs[16384 + i];
    }
    for (int i = tid; i < 1024; i += 128)
        ((float4*)hsh)[i] = ((const float4*)(tabs + 4096))[i];
    if (tid == 0) seq_raw[0] = 0;
    {
        const int4* s4 = (const int4*)(seq + b * L_SEQ);
        for (int i = tid; i < 512; i += 128) {
            int4 vv = s4[i];
            seq_sh[i * 4 + 0] = vv.x; seq_sh[i * 4 + 1] = vv.y;
            seq_sh[i * 4 + 2] = vv.z; seq_sh[i * 4 + 3] = vv.w;
        }
    }
    __syncthreads();

    // ---- init: u = k_tokL  =>  gf_v = G[v][tokL];  w = vocab-space r ----
    const int tokL = seq_sh[NPOS];
    float gf = gt[m * 4160 + lane * 65 + tokL];
    float w  = 0.f;
    const float invL = 1.0f / (float)L_SEQ;
    const int  rowV = m * 4160 + lane * 65;      // Gc base row (element index)

    for (int ci = 0; ci < NCH; ++ci) {
        if (__all(fabsf(gf) < 1e-6f)) break;     // residual-based exit (per wave)

        const int t_ = NPOS - TCH * (ci + 1);    // 2015, 1983, ..., -1

        // ---- batch 1: chunk tokens (uniform b128 + per-lane b32) ----
        int tta[TCH];
        {
            const int4* tp4 = (const int4*)&seq_sh[t_];
            #pragma unroll
            for (int k2 = 0; k2 < 8; ++k2) {
                int4 vv = tp4[k2];
                tta[4*k2+0] = vv.x; tta[4*k2+1] = vv.y;
                tta[4*k2+2] = vv.z; tta[4*k2+3] = vv.w;
            }
        }
        const int tq = seq_sh[t_ + q];           // per-lane token at position q

        // ---- batch 2: bpermute + aW + Gc (all independent, one lgkm wall) ----
        const float gq = __int_as_float(
            __builtin_amdgcn_ds_bpermute(tq << 2, __float_as_int(gf)));

        const int rowQ = m * 4160 + tq * 65;
        float aW[TCH];
        {
            const float cfs = m ? invL : 0.0f;
            float cf = m ? (float)(t_ + 1) * invL : 1.0f;
            #pragma unroll
            for (int ps = 1; ps < TCH; ++ps) {
                cf += cfs;
                const float gv = gt[rowQ + tta[ps]];
                aW[ps] = (q < ps) ? cf * gv : 0.f;
            }
        }
        float Gc[TCH];
        #pragma unroll
        for (int qq = 0; qq < TCH; ++qq) Gc[qq] = gt[rowV + tta[qq]];

        // FENCE: forbid sinking the gathers into the solve chain.
        __builtin_amdgcn_sched_barrier(0);

        // ---- triangular solve: chain = readlane + fma per step ----
        float dv = gq;
        #pragma unroll
        for (int ps = TCH - 1; ps >= 1; --ps)
            dv = fmaf(-aW[ps], rdlane(dv, ps), dv);

        // ---- e = c_q d_q (masked for p<0 in final chunk) ----
        const int   pq = t_ + q;
        const float cq = m ? (float)(pq + 1) * invL : 1.0f;
        const float ev = (pq >= 0) ? cq * dv : 0.f;

        // ---- state updates (VALU only): gf -= sum e G-col ; w_v += e[ta==v] ----
        float gA = 0.f, gB = 0.f, wA = 0.f, wB = 0.f;
        #pragma unroll
        for (int qq = 0; qq < TCH; qq += 2) {
            const float e0 = rdlane(ev, qq);
            const float e1 = rdlane(ev, qq + 1);
            gA = fmaf(e0, Gc[qq],     gA);
            gB = fmaf(e1, Gc[qq + 1], gB);
            wA += (lane == tta[qq])     ? e0 : 0.f;
            wB += (lane == tta[qq + 1]) ? e1 : 0.f;
        }
        gf -= gA + gB;
        w  += wA + wB;
    }

    // ---- final: r_q = sum_v w_v * h[v][q] ----
    float r = 0.f;
    #pragma unroll 8
    for (int v = 0; v < 64; ++v) {
        const float wv = rdlane(w, v);
        r = fmaf(wv, hsh[(m * 64 + v) * 32 + q], r);
    }

    if (lane < 32)
        rbuf[b * 64 + m * 32 + q] = r;   // [rs | re] = concat order
}

// ---------------- Kernel C: output projection ------------------------------
__global__ void out_kernel(const float* __restrict__ rbuf,
                           const float* __restrict__ wrp, const float* __restrict__ brp,
                           const float* __restrict__ wout, const float* __restrict__ bout,
                           float* __restrict__ out) {
    const int b = blockIdx.x;
    const int t = threadIdx.x;
    __shared__ float rsh[64];
    __shared__ float ysh[64];

    rsh[t] = rbuf[b * 64 + t];
    __syncthreads();

    float y = brp[t];
    #pragma unroll 8
    for (int k = 0; k < 64; ++k) y += rsh[k] * wrp[k * 64 + t];
    ysh[t] = y;
    __syncthreads();

    float o = bout[t];
    #pragma unroll 8
    for (int k = 0; k < 64; ++k) o += ysh[k] * wout[k * 64 + t];
    out[b * 64 + t] = o;
}

// ---------------- launch ----------------------------------------------------
extern "C" void kernel_launch(void* const* d_in, const int* in_sizes, int n_in,
                              void* d_out, int out_size, void* d_ws, size_t ws_size,
                              hipStream_t stream) {
    const int*   seq   = (const int*)  d_in[0];
    const float* embed = (const float*)d_in[1];
    const float* w1    = (const float*)d_in[2];
    const float* b1    = (const float*)d_in[3];
    const float* w2    = (const float*)d_in[4];
    const float* b2    = (const float*)d_in[5];
    const float* ln_g  = (const float*)d_in[6];
    const float* ln_b  = (const float*)d_in[7];
    const float* ws    = (const float*)d_in[8];
    const float* bs    = (const float*)d_in[9];
    const float* we    = (const float*)d_in[10];
    const float* be    = (const float*)d_in[11];
    const float* wrp   = (const float*)d_in[12];
    const float* brp   = (const float*)d_in[13];
    const float* wout  = (const float*)d_in[14];
    const float* bout  = (const float*)d_in[15];

    float* tabs = (float*)d_ws;              // tables + gram
    float* gout = tabs + 16384;              // gram [2][64][64]
    float* rbuf = tabs + 24576;              // r vectors [256][64]

    build_tables<<<64, 64, 0, stream>>>(embed, w1, b1, w2, b2, ln_g, ln_b,
                                        ws, bs, we, be, tabs);
    gram_kernel<<<64, 128, 0, stream>>>(tabs, gout);
    scan_kernel<<<256, 128, 0, stream>>>(seq, tabs, rbuf);
    out_kernel<<<256, 64, 0, stream>>>(rbuf, wrp, brp, wout, bout, (float*)d_out);
}